// Round 4
// baseline (333.710 us; speedup 1.0000x reference)
//
#include <hip/hip_runtime.h>

#define NMAT 2048

typedef float f32x4 __attribute__((ext_vector_type(4)));

__device__ __forceinline__ float4 f4fma(float a, float4 b, float4 c) {
    return make_float4(fmaf(a, b.x, c.x), fmaf(a, b.y, c.y),
                       fmaf(a, b.z, c.z), fmaf(a, b.w, c.w));
}
__device__ __forceinline__ float4 f4scale(float a, float4 b) {
    return make_float4(a * b.x, a * b.y, a * b.z, a * b.w);
}
__device__ __forceinline__ float4 f4add(float4 a, float4 b) {
    return make_float4(a.x + b.x, a.y + b.y, a.z + b.z, a.w + b.w);
}

// One pass over `in`: rowsum, colsum, diag, trace, totsum.
// 256 blocks x 256 threads; block b owns rows 8b..8b+7, all 2048 cols.
__global__ __launch_bounds__(256) void k_stats(const float* __restrict__ in,
                                               float* __restrict__ rowsum,
                                               float* __restrict__ diag,
                                               float* __restrict__ colsum,
                                               float* __restrict__ scal) {
    const int t = threadIdx.x;
    const int r0 = blockIdx.x * 8;
    __shared__ float lrs[8][256];
    float4 c0 = make_float4(0.f, 0.f, 0.f, 0.f);
    float4 c1 = make_float4(0.f, 0.f, 0.f, 0.f);
#pragma unroll
    for (int r = 0; r < 8; ++r) {
        const float4* row = (const float4*)(in + (size_t)(r0 + r) * NMAT);
        float4 v0 = row[t];
        float4 v1 = row[t + 256];
        c0.x += v0.x; c0.y += v0.y; c0.z += v0.z; c0.w += v0.w;
        c1.x += v1.x; c1.y += v1.y; c1.z += v1.z; c1.w += v1.w;
        lrs[r][t] = ((v0.x + v0.y) + (v0.z + v0.w)) +
                    ((v1.x + v1.y) + (v1.z + v1.w));
    }
    atomicAdd(&colsum[4 * t + 0], c0.x);
    atomicAdd(&colsum[4 * t + 1], c0.y);
    atomicAdd(&colsum[4 * t + 2], c0.z);
    atomicAdd(&colsum[4 * t + 3], c0.w);
    atomicAdd(&colsum[1024 + 4 * t + 0], c1.x);
    atomicAdd(&colsum[1024 + 4 * t + 1], c1.y);
    atomicAdd(&colsum[1024 + 4 * t + 2], c1.z);
    atomicAdd(&colsum[1024 + 4 * t + 3], c1.w);
    __syncthreads();
    {
        const int row = t >> 5;
        const int lane = t & 31;
        float s = 0.f;
#pragma unroll
        for (int k = 0; k < 8; ++k) s += lrs[row][lane + 32 * k];
        s += __shfl_down(s, 16);
        s += __shfl_down(s, 8);
        s += __shfl_down(s, 4);
        s += __shfl_down(s, 2);
        s += __shfl_down(s, 1);
        if (lane == 0) {
            rowsum[r0 + row] = s;
            atomicAdd(&scal[1], s);   // totsum
        }
    }
    if (t < 8) {
        const int r = r0 + t;
        const float d = in[(size_t)r * NMAT + r];
        diag[r] = d;
        atomicAdd(&scal[0], d);       // trace
    }
}

// Full transpose: T[a][b] = in[b][a]. 64x64 LDS tiles, 32x32 grid.
__global__ __launch_bounds__(256) void k_tr(const float* __restrict__ in,
                                            float* __restrict__ T) {
    __shared__ float tile[64][65];
    const int t = threadIdx.x;
    const int bi = blockIdx.y * 64;     // row range of in
    const int bj = blockIdx.x * 64;     // col range of in
    const int c4 = t & 15;              // float4 column
    const int r = t >> 4;               // 0..15
#pragma unroll
    for (int s = 0; s < 4; ++s) {
        const int row = s * 16 + r;
        const float4 v = *(const float4*)(in + (size_t)(bi + row) * NMAT +
                                          bj + c4 * 4);
        tile[row][c4 * 4 + 0] = v.x;
        tile[row][c4 * 4 + 1] = v.y;
        tile[row][c4 * 4 + 2] = v.z;
        tile[row][c4 * 4 + 3] = v.w;
    }
    __syncthreads();
#pragma unroll
    for (int s = 0; s < 4; ++s) {
        const int jj = s * 16 + r;
        float4 v;
        v.x = tile[c4 * 4 + 0][jj];
        v.y = tile[c4 * 4 + 1][jj];
        v.z = tile[c4 * 4 + 2][jj];
        v.w = tile[c4 * 4 + 3][jj];
        *(float4*)(T + (size_t)(bj + jj) * NMAT + bi + c4 * 4) = v;
    }
}

// Per-j base table B4 (Q(j) + trace/totsum ones-terms) and diagonal table D4.
__global__ __launch_bounds__(256) void k_tables(const float* __restrict__ w,
                                                const float* __restrict__ rowsum,
                                                const float* __restrict__ diag,
                                                const float* __restrict__ colsum,
                                                const float* __restrict__ scal,
                                                float4* __restrict__ B4,
                                                float4* __restrict__ D4) {
    const int idx = blockIdx.x * 256 + threadIdx.x;   // i*4 + og
    const int i = idx >> 2;
    const int og = idx & 3;
    const float di = diag[i], rs = rowsum[i], cs = colsum[i];
    const float tr = scal[0], ts = scal[1];
    const float4* W = (const float4*)w;   // W[k*4+og] = w[k][og*4..og*4+3]
    float4 B = f4scale(di, W[5 * 4 + og]);
    B = f4fma(rs, W[6 * 4 + og], B);
    B = f4fma(cs, W[7 * 4 + og], B);
    B = f4fma(tr, W[13 * 4 + og], B);
    B = f4fma(ts, W[14 * 4 + og], B);
    float4 D = f4scale(di, W[0 * 4 + og]);
    D = f4fma(rs, W[1 * 4 + og], D);
    D = f4fma(cs, W[2 * 4 + og], D);
    D = f4fma(tr, W[3 * 4 + og], D);
    D = f4fma(ts, W[4 * 4 + og], D);
    B4[idx] = B;
    D4[idx] = D;
}

// Main, fill-shaped: block owns output row i (128 KB CONTIGUOUS), sweeps j
// linearly. Per wave-pass: 1 KB lane-linear B4 load, two 64 B row loads
// (in-row and pre-transposed T-row, both coalesced), 1 KB contiguous cached
// store. i-side terms are block-uniform scalars folded into rt once.
__global__ __launch_bounds__(256) void k_main_lin(const float* __restrict__ in,
                                                  const float* __restrict__ T,
                                                  const float* __restrict__ w,
                                                  const float* __restrict__ rowsum,
                                                  const float* __restrict__ diag,
                                                  const float* __restrict__ colsum,
                                                  const float4* __restrict__ B4,
                                                  const float4* __restrict__ D4,
                                                  float4* __restrict__ out4) {
    const int t = threadIdx.x;
    const int og = t & 3;
    const int jl = t >> 2;               // 0..63
    const int i = blockIdx.x;
    const float4* W = (const float4*)w;
    const float4 w11 = W[11 * 4 + og];
    const float4 w12 = W[12 * 4 + og];
    // Block-uniform i-terms: di*w8 + rsi*w9 + csi*w10.
    const float di = diag[i], rsi = rowsum[i], csi = colsum[i];
    float4 rt = f4scale(di, W[8 * 4 + og]);
    rt = f4fma(rsi, W[9 * 4 + og], rt);
    rt = f4fma(csi, W[10 * 4 + og], rt);
    const float4 d4 = D4[i * 4 + og];
    const float* arow = in + (size_t)i * NMAT;
    const float* trow = T + (size_t)i * NMAT;
    float4* orow = out4 + (size_t)i * (NMAT * 4);
#pragma unroll 4
    for (int p = 0; p < 32; ++p) {
        const int j = p * 64 + jl;
        const float a = arow[j];         // in[i][j], 64 B/wave
        const float at = trow[j];        // in[j][i] via T, 64 B/wave
        const float4 b = B4[p * 256 + t];   // lane-linear 1 KB/wave
        float4 r = f4add(b, rt);
        r = f4fma(a, w12, r);
        r = f4fma(at, w11, r);
        if (j == i) {                    // 4 lanes, 1 pass per block
            r.x += d4.x; r.y += d4.y; r.z += d4.z; r.w += d4.w;
        }
        orow[p * 256 + t] = r;           // 4 KB contiguous per block-pass
    }
}

// Fallback (round-0 proven path) if workspace can't hold the transpose.
__global__ __launch_bounds__(256) void k_main_tiled(const float* __restrict__ in,
                                                    const float* __restrict__ w,
                                                    const float* __restrict__ rowsum,
                                                    const float* __restrict__ diag,
                                                    const float* __restrict__ colsum,
                                                    const float* __restrict__ scal,
                                                    float4* __restrict__ out4) {
    const int t = threadIdx.x;
    const int og = t & 3;
    const int tj = (t >> 2) & 31;
    const int half = t >> 7;
    const int j = blockIdx.x * 32 + tj;
    const int i0 = blockIdx.y * 32;
    const bool dblk = (blockIdx.x == blockIdx.y);
    const float4* W = (const float4*)w;
    const float4 w8 = W[8 * 4 + og], w9 = W[9 * 4 + og], w10 = W[10 * 4 + og];
    const float4 w11 = W[11 * 4 + og], w12 = W[12 * 4 + og];
    const float tr = scal[0], ts = scal[1];
    float4 base = f4scale(diag[j], W[5 * 4 + og]);
    base = f4fma(rowsum[j], W[6 * 4 + og], base);
    base = f4fma(colsum[j], W[7 * 4 + og], base);
    base = f4fma(tr, W[13 * 4 + og], base);
    base = f4fma(ts, W[14 * 4 + og], base);
    const size_t jrow = (size_t)j * NMAT;
#pragma unroll 4
    for (int it = 0; it < 16; ++it) {
        const int i = i0 + half + 2 * it;
        const float di = diag[i];
        const float rsi = rowsum[i];
        const float csi = colsum[i];
        const float a = in[(size_t)i * NMAT + j];
        const float at = in[jrow + i];
        float4 r = f4fma(di, w8, base);
        r = f4fma(rsi, w9, r);
        r = f4fma(csi, w10, r);
        r = f4fma(a, w12, r);
        r = f4fma(at, w11, r);
        if (dblk && i == j) {
            float4 dd = f4scale(di, W[0 * 4 + og]);
            dd = f4fma(rsi, W[1 * 4 + og], dd);
            dd = f4fma(csi, W[2 * 4 + og], dd);
            dd = f4fma(tr, W[3 * 4 + og], dd);
            dd = f4fma(ts, W[4 * 4 + og], dd);
            r.x += dd.x; r.y += dd.y; r.z += dd.z; r.w += dd.w;
        }
        f32x4 rv = {r.x, r.y, r.z, r.w};
        __builtin_nontemporal_store(
            rv, (f32x4*)&out4[((size_t)i * NMAT + j) * 4 + og]);
    }
}

extern "C" void kernel_launch(void* const* d_in, const int* in_sizes, int n_in,
                              void* d_out, int out_size, void* d_ws, size_t ws_size,
                              hipStream_t stream) {
    const float* in = (const float*)d_in[0];   // [2048, 2048] f32
    const float* w = (const float*)d_in[1];    // [15, 16] f32
    float* ws = (float*)d_ws;

    // Workspace layout (floats):
    //   [0,2048)        colsum  (atomic-accumulated; zeroed below)
    //   [2048,2050)     scal: trace, totsum (atomic; zeroed below)
    //   [2056,4104)     rowsum
    //   [4104,6152)     diag
    //   [8192, +4.19M)  T = in^T                (16 MiB)
    //   then B4 (8192 float4), D4 (8192 float4)
    float* colsum = ws;
    float* scal = ws + 2048;
    float* rowsum = ws + 2056;
    float* diag = ws + 4104;
    const size_t T_OFF = 8192;
    const size_t T_FLOATS = (size_t)NMAT * NMAT;
    const size_t B_OFF = T_OFF + T_FLOATS;
    const size_t D_OFF = B_OFF + 4 * 8192;
    const size_t NEED_BYTES = (D_OFF + 4 * 8192) * sizeof(float);

    hipMemsetAsync(d_ws, 0, 2050 * sizeof(float), stream);
    k_stats<<<256, 256, 0, stream>>>(in, rowsum, diag, colsum, scal);

    if (ws_size >= NEED_BYTES) {
        float* T = ws + T_OFF;
        float4* B4 = (float4*)(ws + B_OFF);
        float4* D4 = (float4*)(ws + D_OFF);
        k_tr<<<dim3(32, 32), 256, 0, stream>>>(in, T);
        k_tables<<<32, 256, 0, stream>>>(w, rowsum, diag, colsum, scal, B4, D4);
        k_main_lin<<<2048, 256, 0, stream>>>(in, T, w, rowsum, diag, colsum,
                                             B4, D4, (float4*)d_out);
    } else {
        k_main_tiled<<<dim3(64, 64), 256, 0, stream>>>(
            in, w, rowsum, diag, colsum, scal, (float4*)d_out);
    }
}